// Round 11
// baseline (328.674 us; speedup 1.0000x reference)
//
#include <hip/hip_runtime.h>
#include <cstdint>
#include <cstddef>

// ExpertMLP: out[e] = gelu(x[e] @ wfc[e]) @ wproj[e]
// E=32, CAP=4096, D=256, H=1024. fp32 in/out, bf16 MFMA internally.
// Round 11 — unfused GEMMs with OPERAND PRE-READ SPRINT:
//   q0 MFMA uses regs read during previous tile's q1; q1's A read under q0's
//   MFMA drain; next tile's B+A(q0) read under q1's drain. vmcnt(4) leading
//   wait guarantees slabs kt AND kt+1. 2 barriers per K-tile (was 4).
// GEMM1 keeps LDS-transpose H epilogue; GEMM2 keeps coalesced f32 stores.
// ne=16 expert groups (H L3-resident), one upfront xcast.

#define NE   32
#define CAPN 4096
#define DDIM 256
#define HDIM 1024

typedef __bf16 bf16x8 __attribute__((ext_vector_type(8)));
typedef __bf16 bf16x4 __attribute__((ext_vector_type(4)));
typedef __bf16 bf16x2 __attribute__((ext_vector_type(2)));
typedef float  f32x4  __attribute__((ext_vector_type(4)));

#define AS1 __attribute__((address_space(1)))
#define AS3 __attribute__((address_space(3)))

__device__ __forceinline__ void gld_lds16(const void* g, void* l) {
  __builtin_amdgcn_global_load_lds((const AS1 uint32_t*)g, (AS3 uint32_t*)l, 16, 0, 0);
}

__device__ __forceinline__ float gelu_f(float x) {
  float x2 = x * x;
  float u  = x * __builtin_fmaf(0.1029432f, x2, 2.3022078f);
  float t  = __builtin_amdgcn_exp2f(u);
  float r  = __builtin_amdgcn_rcpf(t + 1.0f);
  return __builtin_fmaf(-x, r, x);
}

#define WV(n)   asm volatile("s_waitcnt vmcnt(" #n ")" ::: "memory")
#define LGKM0() asm volatile("s_waitcnt lgkmcnt(0)" ::: "memory")
#define SB0()   __builtin_amdgcn_sched_barrier(0)
#define BAR()   __builtin_amdgcn_s_barrier()
#define MFMA_(a, b, c) __builtin_amdgcn_mfma_f32_16x16x32_bf16(a, b, c, 0, 0, 0)

// ---------------- pre-pass: transpose + cast fp32 -> bf16 -------------------
__global__ __launch_bounds__(256) void tcast_kernel(const float* __restrict__ in,
                                                    __bf16* __restrict__ outp,
                                                    int R, int C) {
  __shared__ __bf16 tl[64][72];
  const int cb = C >> 6;
  const int nb = (R >> 6) * cb;
  const int b  = blockIdx.x;
  const int e  = b / nb;
  const int t  = b - e * nb;
  const int br = t / cb;
  const int bc = t - br * cb;
  const float* src = in + ((size_t)e * R + (size_t)br * 64) * C + (size_t)bc * 64;
#pragma unroll
  for (int i = 0; i < 16; ++i) {
    int idx = i * 256 + threadIdx.x;
    int r = idx >> 6, c = idx & 63;
    tl[c][r] = (__bf16)src[(size_t)r * C + c];
  }
  __syncthreads();
  __bf16* dst = outp + ((size_t)e * C + (size_t)bc * 64) * R + (size_t)br * 64;
#pragma unroll
  for (int i = 0; i < 8; ++i) {
    int idx = i * 512 + threadIdx.x * 2;
    int c = idx >> 6, r = idx & 63;
    bf16x2 p;
    p[0] = tl[c][r];
    p[1] = tl[c][r + 1];
    *(bf16x2*)(dst + (size_t)c * R + r) = p;
  }
}

// ---------------- x fp32 -> bf16 flat cast (all experts, once) --------------
__global__ __launch_bounds__(256) void xcast_kernel(const float* __restrict__ in,
                                                    __bf16* __restrict__ outp,
                                                    long n8) {
  long i = (long)blockIdx.x * 256 + threadIdx.x;
  const long stride = (long)gridDim.x * 256;
  for (; i < n8; i += stride) {
    float4 a0 = ((const float4*)in)[2 * i];
    float4 a1 = ((const float4*)in)[2 * i + 1];
    bf16x8 v;
    v[0] = (__bf16)a0.x; v[1] = (__bf16)a0.y; v[2] = (__bf16)a0.z; v[3] = (__bf16)a0.w;
    v[4] = (__bf16)a1.x; v[5] = (__bf16)a1.y; v[6] = (__bf16)a1.z; v[7] = (__bf16)a1.w;
    ((bf16x8*)outp)[i] = v;
  }
}

// ---------------- sprint GEMM (256x256 tile, BK=32, ring-4) -----------------
// G1E: A=wfcT[e_g] rows h, B=Xb[e_g] rows m, C=H[e_l] (LDS-transpose epi)
// else: A=Hb[e_l] rows m,  B=wprojT[e_g] rows d, C=out[e_g] (coalesced epi)
template <int NKT, int NT, int NRA, int RSA, int RSB, bool G1E>
__global__ __launch_bounds__(512, 1) void gemm_sp(
    const __bf16* __restrict__ Ap, const __bf16* __restrict__ Bp,
    void* __restrict__ Cp, int e0) {
  extern __shared__ char smem[];
  const int tid = threadIdx.x;
  const int l15 = tid & 15, l4 = (tid >> 4) & 3, w = tid >> 6;
  const int wr = w & 1, wq = w >> 1;

  const int epb = 16 * NT;
  const int bid = blockIdx.x;
  const int e_l = bid / epb;
  const int t   = bid - e_l * epb;
  const int mt  = t / NT, ct = t - mt * NT;
  const int m0  = mt << 8, r0 = ct << 8;
  const int e_g = e0 + e_l;

  const int eA = G1E ? e_g : e_l;
  const int ra0 = G1E ? r0 : m0;
  const __bf16* Ab = Ap + ((size_t)eA * NRA + ra0) * RSA;
  const __bf16* Bb = G1E ? (Bp + ((size_t)e_g * CAPN + m0) * RSB)
                         : (Bp + (size_t)e_g * DDIM * RSB);

  const int sr  = tid >> 2;
  const int ssl = (tid & 3) ^ ((sr >> 1) & 3);
  char* dstA = smem + tid * 16;
  char* dstB = smem + 65536 + tid * 16;

#define STAGE_A(T_) do {                                                       \
    const __bf16* s_ = Ab + (size_t)sr * RSA + (T_) * 32 + ssl * 8;            \
    gld_lds16(s_,             dstA + ((T_) & 3) * 16384);                      \
    gld_lds16(s_ + 128 * RSA, dstA + ((T_) & 3) * 16384 + 8192);               \
  } while (0)
#define STAGE_B(T_) do {                                                       \
    const __bf16* s_ = Bb + (size_t)sr * RSB + (T_) * 32 + ssl * 8;            \
    gld_lds16(s_,             dstB + ((T_) & 3) * 16384);                      \
    gld_lds16(s_ + 128 * RSB, dstB + ((T_) & 3) * 16384 + 8192);               \
  } while (0)

  const int physk = (l4 ^ ((l15 >> 1) & 3)) * 16;
  const int aoff  = (wr * 128 + l15) * 64 + physk;          // + rf*1024
  const int boff  = 65536 + (wq * 64 + l15) * 64 + physk;   // + fm*1024

  f32x4 zero = 0.0f;
  f32x4 acc[8][4];
#pragma unroll
  for (int a = 0; a < 8; ++a)
#pragma unroll
    for (int b = 0; b < 4; ++b) acc[a][b] = zero;

  bf16x8 bxE[4], bxO[4], af0[4], af1[4];

  // TILE: leading WV+BAR; q0 {lgkm0; read af1(kt); stage A(kt+3);
  //   MFMA acc[0..3] (af0 x CUR)}; q1 {lgkm0; read NXT bx + af0 of kt+1;
  //   stage B(kt+3); MFMA acc[4..7] (af1 x CUR)}; trailing BAR.
#define TILE(KT, CUR, NXT, WVN, PRE0, PREN) do {                               \
    WV(WVN); BAR(); SB0();                                                     \
    const int buf_ = ((KT) & 3) * 16384;                                       \
    if (PRE0) {                                                                \
      _Pragma("unroll") for (int i_ = 0; i_ < 4; ++i_) {                       \
        CUR[i_] = *(const bf16x8*)(smem + buf_ + boff + i_ * 1024);            \
        af0[i_] = *(const bf16x8*)(smem + buf_ + aoff + i_ * 1024);            \
      }                                                                        \
    }                                                                          \
    LGKM0(); SB0();                                                            \
    _Pragma("unroll") for (int i_ = 0; i_ < 4; ++i_)                           \
      af1[i_] = *(const bf16x8*)(smem + buf_ + aoff + (4 + i_) * 1024);        \
    if ((KT) + 3 < NKT) STAGE_A((KT) + 3);                                     \
    __builtin_amdgcn_s_setprio(1);                                             \
    _Pragma("unroll") for (int rf_ = 0; rf_ < 4; ++rf_)                        \
      _Pragma("unroll") for (int fm_ = 0; fm_ < 4; ++fm_)                      \
        acc[rf_][fm_] = MFMA_(af0[rf_], CUR[fm_], acc[rf_][fm_]);              \
    __builtin_amdgcn_s_setprio(0);                                             \
    LGKM0(); SB0();                                                            \
    if (PREN) {                                                                \
      const int nbuf_ = (((KT) + 1) & 3) * 16384;                              \
      _Pragma("unroll") for (int i_ = 0; i_ < 4; ++i_) {                       \
        NXT[i_] = *(const bf16x8*)(smem + nbuf_ + boff + i_ * 1024);           \
        af0[i_] = *(const bf16x8*)(smem + nbuf_ + aoff + i_ * 1024);           \
      }                                                                        \
    }                                                                          \
    if ((KT) + 3 < NKT) STAGE_B((KT) + 3);                                     \
    __builtin_amdgcn_s_setprio(1);                                             \
    _Pragma("unroll") for (int rf_ = 0; rf_ < 4; ++rf_)                        \
      _Pragma("unroll") for (int fm_ = 0; fm_ < 4; ++fm_)                      \
        acc[4 + rf_][fm_] = MFMA_(af1[rf_], CUR[fm_], acc[4 + rf_][fm_]);      \
    __builtin_amdgcn_s_setprio(0);                                             \
    BAR(); SB0();                                                              \
  } while (0)

  // prologue: 3 tiles in flight (12 gld_lds, tile-major order)
  STAGE_A(0); STAGE_B(0);
  STAGE_A(1); STAGE_B(1);
  STAGE_A(2); STAGE_B(2);

  TILE(0, bxE, bxO, 4, true, true);
  TILE(1, bxO, bxE, 4, false, true);
#pragma unroll 2
  for (int kt = 2; kt < NKT - 2; kt += 2) {
    TILE(kt,     bxE, bxO, 4, false, true);
    TILE(kt + 1, bxO, bxE, 4, false, true);
  }
  TILE(NKT - 2, bxE, bxO, 0, false, true);
  TILE(NKT - 1, bxO, bxE, 0, false, false);

  // ---- epilogue ----
  if constexpr (G1E) {
    // GELU -> LDS [256 m][256 h] swizzled -> coalesced bf16x8 writes
#pragma unroll
    for (int rf = 0; rf < 8; ++rf) {
#pragma unroll
      for (int fm = 0; fm < 4; ++fm) {
        const int hl = wr * 128 + rf * 16 + l4 * 4;
        const int ml = wq * 64 + fm * 16 + l15;
        bf16x4 hv;
#pragma unroll
        for (int j = 0; j < 4; ++j) hv[j] = (__bf16)gelu_f(acc[rf][fm][j]);
        const int s    = hl >> 3;
        const int half = (hl >> 2) & 1;
        const int phys = (s & 24) | ((s & 7) ^ (ml & 7));
        *(bf16x4*)(smem + ml * 512 + phys * 16 + half * 8) = hv;
      }
    }
    LGKM0(); BAR(); SB0();
    __bf16* Hp = (__bf16*)Cp + ((size_t)(e_l * CAPN + m0)) * HDIM + r0;
#pragma unroll
    for (int i = 0; i < 16; ++i) {
      const int sid = i * 512 + tid;
      const int ml  = sid >> 5;
      const int s   = sid & 31;
      const int phys = (s & 24) | ((s & 7) ^ (ml & 7));
      bf16x8 v = *(const bf16x8*)(smem + ml * 512 + phys * 16);
      *(bf16x8*)(Hp + (size_t)ml * HDIM + s * 8) = v;
    }
  } else {
    // D reg axis = m, lane axis = d -> line-coalesced f32 stores
    float* Op = (float*)Cp + ((size_t)(e_g * CAPN + m0)) * DDIM;
#pragma unroll
    for (int rf = 0; rf < 8; ++rf) {
#pragma unroll
      for (int fm = 0; fm < 4; ++fm) {
        const int d = wq * 64 + fm * 16 + l15;
#pragma unroll
        for (int j = 0; j < 4; ++j) {
          const int m = wr * 128 + rf * 16 + l4 * 4 + j;
          Op[(size_t)m * DDIM + d] = acc[rf][fm][j];
        }
      }
    }
  }
#undef STAGE_A
#undef STAGE_B
#undef TILE
}

extern "C" void kernel_launch(void* const* d_in, const int* in_sizes, int n_in,
                              void* d_out, int out_size, void* d_ws, size_t ws_size,
                              hipStream_t stream) {
  (void)in_sizes; (void)n_in; (void)out_size;
  const float* x     = (const float*)d_in[0];
  const float* wfc   = (const float*)d_in[1];   // [E][D][H]
  const float* wproj = (const float*)d_in[2];   // [E][H][D]
  float* out = (float*)d_out;

  // ws: wfcT 16.8M | wprojT 16.8M | Xb(all E) 67.1M | Hb(ne) ne*8.39M
  const size_t WSZ  = (size_t)NE * DDIM * HDIM * sizeof(__bf16);
  const size_t XSZ  = (size_t)NE * CAPN * DDIM * sizeof(__bf16);
  const size_t HPER = (size_t)CAPN * HDIM * sizeof(__bf16);  // 8.39 MB/expert
  int ne = 16;
  while (ne > 1 && 2 * WSZ + XSZ + (size_t)ne * HPER > ws_size) ne >>= 1;

  __bf16* wfcT   = (__bf16*)d_ws;
  __bf16* wprojT = (__bf16*)((char*)d_ws + WSZ);
  __bf16* Xb     = (__bf16*)((char*)d_ws + 2 * WSZ);
  __bf16* Hb     = (__bf16*)((char*)d_ws + 2 * WSZ + XSZ);

  hipFuncSetAttribute((const void*)&gemm_sp<8, 4, 1024, 256, 256, true>,
                      hipFuncAttributeMaxDynamicSharedMemorySize, 131072);
  hipFuncSetAttribute((const void*)&gemm_sp<32, 1, 4096, 1024, 1024, false>,
                      hipFuncAttributeMaxDynamicSharedMemorySize, 131072);

  tcast_kernel<<<dim3(NE * 64), dim3(256), 0, stream>>>(wfc, wfcT, DDIM, HDIM);
  tcast_kernel<<<dim3(NE * 64), dim3(256), 0, stream>>>(wproj, wprojT, HDIM, DDIM);
  xcast_kernel<<<dim3(2048), dim3(256), 0, stream>>>(x, Xb, (long)NE * CAPN * DDIM / 8);

  const int ngroups = NE / ne;
  for (int g = 0; g < ngroups; ++g) {
    const int e0 = g * ne;
    gemm_sp<8, 4, 1024, 256, 256, true>
        <<<dim3(ne * 64), dim3(512), 131072, stream>>>(
            wfcT, Xb, Hb, e0);
    gemm_sp<32, 1, 4096, 1024, 1024, false>
        <<<dim3(ne * 16), dim3(512), 131072, stream>>>(
            Hb, wprojT, out, e0);
  }
}

// Round 12
// 321.486 us; speedup vs baseline: 1.0224x; 1.0224x over previous
//
#include <hip/hip_runtime.h>
#include <cstdint>
#include <cstddef>

// ExpertMLP: out[e] = gelu(x[e] @ wfc[e]) @ wproj[e]
// E=32, CAP=4096, D=256, H=1024. fp32 in/out, bf16 MFMA internally.
// Round 12 — FAITHFUL m201 8-phase grain: 16-MFMA phases, reads pre-barrier,
// lgkm0 post-barrier (+sched_barrier(0) per rule 18), 2 gld_lds per phase,
// vmcnt(4) once per K-tile at the LAST phase (guards the NEXT tile's buffer),
// ring-4 slabs, distance-2 prefetch, drain only at the tail.
// GEMM1 keeps LDS-transpose H epilogue; GEMM2 keeps coalesced f32 stores.

#define NE   32
#define CAPN 4096
#define DDIM 256
#define HDIM 1024

typedef __bf16 bf16x8 __attribute__((ext_vector_type(8)));
typedef __bf16 bf16x4 __attribute__((ext_vector_type(4)));
typedef __bf16 bf16x2 __attribute__((ext_vector_type(2)));
typedef float  f32x4  __attribute__((ext_vector_type(4)));

#define AS1 __attribute__((address_space(1)))
#define AS3 __attribute__((address_space(3)))

__device__ __forceinline__ void gld_lds16(const void* g, void* l) {
  __builtin_amdgcn_global_load_lds((const AS1 uint32_t*)g, (AS3 uint32_t*)l, 16, 0, 0);
}

__device__ __forceinline__ float gelu_f(float x) {
  float x2 = x * x;
  float u  = x * __builtin_fmaf(0.1029432f, x2, 2.3022078f);
  float t  = __builtin_amdgcn_exp2f(u);
  float r  = __builtin_amdgcn_rcpf(t + 1.0f);
  return __builtin_fmaf(-x, r, x);
}

#define WV(n)   asm volatile("s_waitcnt vmcnt(" #n ")" ::: "memory")
#define LGKM0() asm volatile("s_waitcnt lgkmcnt(0)" ::: "memory")
#define SB0()   __builtin_amdgcn_sched_barrier(0)
#define BAR()   __builtin_amdgcn_s_barrier()
#define MFMA_(a, b, c) __builtin_amdgcn_mfma_f32_16x16x32_bf16(a, b, c, 0, 0, 0)

// ---------------- pre-pass: transpose + cast fp32 -> bf16 -------------------
__global__ __launch_bounds__(256) void tcast_kernel(const float* __restrict__ in,
                                                    __bf16* __restrict__ outp,
                                                    int R, int C) {
  __shared__ __bf16 tl[64][72];
  const int cb = C >> 6;
  const int nb = (R >> 6) * cb;
  const int b  = blockIdx.x;
  const int e  = b / nb;
  const int t  = b - e * nb;
  const int br = t / cb;
  const int bc = t - br * cb;
  const float* src = in + ((size_t)e * R + (size_t)br * 64) * C + (size_t)bc * 64;
#pragma unroll
  for (int i = 0; i < 16; ++i) {
    int idx = i * 256 + threadIdx.x;
    int r = idx >> 6, c = idx & 63;
    tl[c][r] = (__bf16)src[(size_t)r * C + c];
  }
  __syncthreads();
  __bf16* dst = outp + ((size_t)e * C + (size_t)bc * 64) * R + (size_t)br * 64;
#pragma unroll
  for (int i = 0; i < 8; ++i) {
    int idx = i * 512 + threadIdx.x * 2;
    int c = idx >> 6, r = idx & 63;
    bf16x2 p;
    p[0] = tl[c][r];
    p[1] = tl[c][r + 1];
    *(bf16x2*)(dst + (size_t)c * R + r) = p;
  }
}

// ---------------- x fp32 -> bf16 flat cast (all experts, once) --------------
__global__ __launch_bounds__(256) void xcast_kernel(const float* __restrict__ in,
                                                    __bf16* __restrict__ outp,
                                                    long n8) {
  long i = (long)blockIdx.x * 256 + threadIdx.x;
  const long stride = (long)gridDim.x * 256;
  for (; i < n8; i += stride) {
    float4 a0 = ((const float4*)in)[2 * i];
    float4 a1 = ((const float4*)in)[2 * i + 1];
    bf16x8 v;
    v[0] = (__bf16)a0.x; v[1] = (__bf16)a0.y; v[2] = (__bf16)a0.z; v[3] = (__bf16)a0.w;
    v[4] = (__bf16)a1.x; v[5] = (__bf16)a1.y; v[6] = (__bf16)a1.z; v[7] = (__bf16)a1.w;
    ((bf16x8*)outp)[i] = v;
  }
}

// ---------------- 8-phase-grain 256x256 GEMM (BK=32) ------------------------
// Wave grid: wh = w&1 (A-row half, 128), wm = w>>1 (B-row quarter, 64).
// acc[a][fm]: A-row = wh*128 + a*16 + (l4*4+j), B-row(col) = wm*64+fm*16+l15.
// Slab [256 rows][32 k] bf16, phys 16B-slot = s ^ ((row>>1)&3).
// LDS: A-ring 4x16KB @0, B-ring 4x16KB @65536 (= 128 KB).
template <int NKT, int NT, int NRA, int RSA, int RSB, bool G1E>
__global__ __launch_bounds__(512, 1) void gemm_8p(
    const __bf16* __restrict__ Ap, const __bf16* __restrict__ Bp,
    void* __restrict__ Cp, int e0) {
  extern __shared__ char smem[];
  const int tid = threadIdx.x;
  const int l15 = tid & 15, l4 = (tid >> 4) & 3, w = tid >> 6;
  const int wh = w & 1, wm = w >> 1;

  const int epb = 16 * NT;
  const int bid = blockIdx.x;
  const int e_l = bid / epb;
  const int t   = bid - e_l * epb;
  const int mt  = t / NT, ct = t - mt * NT;
  const int m0  = mt << 8, r0 = ct << 8;
  const int e_g = e0 + e_l;

  const int eA  = G1E ? e_g : e_l;
  const int ra0 = G1E ? r0 : m0;
  const __bf16* Ab = Ap + ((size_t)eA * NRA + ra0) * RSA;
  const __bf16* Bb = G1E ? (Bp + ((size_t)e_g * CAPN + m0) * RSB)
                         : (Bp + (size_t)e_g * DDIM * RSB);

  // stage lane geometry: 1 load/thread per 8KB half (rows H*128 + tid>>2)
  const int sr  = tid >> 2;                      // 0..127
  const int ssl = (tid & 3) ^ ((tid >> 3) & 3);  // swizzled source slot
  char* dstA = smem + tid * 16;
  char* dstB = smem + 65536 + tid * 16;

#define ST_AH(T_, H_) do {                                                     \
    const __bf16* s_ = Ab + (size_t)((H_) * 128 + sr) * RSA + (T_) * 32 + ssl * 8; \
    gld_lds16(s_, dstA + ((T_) & 3) * 16384 + (H_) * 8192);                    \
  } while (0)
#define ST_BH(T_, H_) do {                                                     \
    const __bf16* s_ = Bb + (size_t)((H_) * 128 + sr) * RSB + (T_) * 32 + ssl * 8; \
    gld_lds16(s_, dstB + ((T_) & 3) * 16384 + (H_) * 8192);                    \
  } while (0)

  const int physk = (l4 ^ ((l15 >> 1) & 3)) * 16;
  const int aoff  = (wh * 128 + l15) * 64 + physk;          // + a*1024
  const int boff  = 65536 + (wm * 64 + l15) * 64 + physk;   // + fm*1024

  f32x4 zero = 0.0f;
  f32x4 acc[8][4];
#pragma unroll
  for (int a = 0; a < 8; ++a)
#pragma unroll
    for (int b = 0; b < 4; ++b) acc[a][b] = zero;

  // prologue: tiles 0,1 staged (8 loads/thread); ensure tile 0 landed
  ST_AH(0, 0); ST_AH(0, 1); ST_BH(0, 0); ST_BH(0, 1);
  ST_AH(1, 0); ST_AH(1, 1); ST_BH(1, 0); ST_BH(1, 1);
  WV(4); BAR();

#pragma unroll 4
  for (int kt = 0; kt < NKT; ++kt) {
    const int abuf = (kt & 3) * 16384;
    bf16x8 bx[4], af0[4], af1[4];

    // ======== phase A: reads -> stage -> bar -> lgkm0 -> 16 MFMA -> bar ====
#pragma unroll
    for (int fm = 0; fm < 4; ++fm)
      bx[fm] = *(const bf16x8*)(smem + abuf + boff + fm * 1024);
#pragma unroll
    for (int rf = 0; rf < 4; ++rf)
      af0[rf] = *(const bf16x8*)(smem + abuf + aoff + rf * 1024);
    if (kt + 2 < NKT) { ST_AH(kt + 2, 0); ST_AH(kt + 2, 1); }
    BAR();
    LGKM0(); SB0();
    __builtin_amdgcn_s_setprio(1);
#pragma unroll
    for (int rf = 0; rf < 4; ++rf)
#pragma unroll
      for (int fm = 0; fm < 4; ++fm)
        acc[rf][fm] = MFMA_(af0[rf], bx[fm], acc[rf][fm]);
    __builtin_amdgcn_s_setprio(0);
    BAR();

    // ======== phase B: reads -> stage -> vmcnt -> bar -> lgkm0 -> MFMA =====
#pragma unroll
    for (int rf = 0; rf < 4; ++rf)
      af1[rf] = *(const bf16x8*)(smem + abuf + aoff + 4096 + rf * 1024);
    if (kt + 2 < NKT) { ST_BH(kt + 2, 0); ST_BH(kt + 2, 1); }
    if (kt <= NKT - 3)      { WV(4); }   // next tile's 4 loads guaranteed
    else if (kt == NKT - 2) { WV(0); }   // tail drain
    BAR();
    LGKM0(); SB0();
    __builtin_amdgcn_s_setprio(1);
#pragma unroll
    for (int rf = 0; rf < 4; ++rf)
#pragma unroll
      for (int fm = 0; fm < 4; ++fm)
        acc[4 + rf][fm] = MFMA_(af1[rf], bx[fm], acc[4 + rf][fm]);
    __builtin_amdgcn_s_setprio(0);
    BAR();
  }

  // ---- epilogue ----
  if constexpr (G1E) {
    // GELU -> LDS [256 m][256 h] swizzled -> coalesced bf16x8 writes
#pragma unroll
    for (int a = 0; a < 8; ++a) {
#pragma unroll
      for (int fm = 0; fm < 4; ++fm) {
        const int hl = wh * 128 + a * 16 + l4 * 4;
        const int ml = wm * 64 + fm * 16 + l15;
        bf16x4 hv;
#pragma unroll
        for (int j = 0; j < 4; ++j) hv[j] = (__bf16)gelu_f(acc[a][fm][j]);
        const int s    = hl >> 3;
        const int half = (hl >> 2) & 1;
        const int phys = (s & 24) | ((s & 7) ^ (ml & 7));
        *(bf16x4*)(smem + ml * 512 + phys * 16 + half * 8) = hv;
      }
    }
    LGKM0(); BAR();
    __bf16* Hp = (__bf16*)Cp + ((size_t)(e_l * CAPN + m0)) * HDIM + r0;
#pragma unroll
    for (int i = 0; i < 16; ++i) {
      const int sid = i * 512 + tid;
      const int ml  = sid >> 5;
      const int s   = sid & 31;
      const int phys = (s & 24) | ((s & 7) ^ (ml & 7));
      bf16x8 v = *(const bf16x8*)(smem + ml * 512 + phys * 16);
      *(bf16x8*)(Hp + (size_t)ml * HDIM + s * 8) = v;
    }
  } else {
    // acc reg axis = m rows, lane axis = d -> line-coalesced f32 stores
    float* Op = (float*)Cp + ((size_t)(e_g * CAPN + m0)) * DDIM;
#pragma unroll
    for (int a = 0; a < 8; ++a) {
#pragma unroll
      for (int fm = 0; fm < 4; ++fm) {
        const int d = wm * 64 + fm * 16 + l15;
#pragma unroll
        for (int j = 0; j < 4; ++j) {
          const int m = wh * 128 + a * 16 + l4 * 4 + j;
          Op[(size_t)m * DDIM + d] = acc[a][fm][j];
        }
      }
    }
  }
#undef ST_AH
#undef ST_BH
}

extern "C" void kernel_launch(void* const* d_in, const int* in_sizes, int n_in,
                              void* d_out, int out_size, void* d_ws, size_t ws_size,
                              hipStream_t stream) {
  (void)in_sizes; (void)n_in; (void)out_size;
  const float* x     = (const float*)d_in[0];
  const float* wfc   = (const float*)d_in[1];   // [E][D][H]
  const float* wproj = (const float*)d_in[2];   // [E][H][D]
  float* out = (float*)d_out;

  // ws: wfcT 16.8M | wprojT 16.8M | Xb(all E) 67.1M | Hb(ne) ne*8.39M
  const size_t WSZ  = (size_t)NE * DDIM * HDIM * sizeof(__bf16);
  const size_t XSZ  = (size_t)NE * CAPN * DDIM * sizeof(__bf16);
  const size_t HPER = (size_t)CAPN * HDIM * sizeof(__bf16);
  int ne = 16;
  while (ne > 1 && 2 * WSZ + XSZ + (size_t)ne * HPER > ws_size) ne >>= 1;

  __bf16* wfcT   = (__bf16*)d_ws;
  __bf16* wprojT = (__bf16*)((char*)d_ws + WSZ);
  __bf16* Xb     = (__bf16*)((char*)d_ws + 2 * WSZ);
  __bf16* Hb     = (__bf16*)((char*)d_ws + 2 * WSZ + XSZ);

  hipFuncSetAttribute((const void*)&gemm_8p<8, 4, 1024, 256, 256, true>,
                      hipFuncAttributeMaxDynamicSharedMemorySize, 131072);
  hipFuncSetAttribute((const void*)&gemm_8p<32, 1, 4096, 1024, 1024, false>,
                      hipFuncAttributeMaxDynamicSharedMemorySize, 131072);

  tcast_kernel<<<dim3(NE * 64), dim3(256), 0, stream>>>(wfc, wfcT, DDIM, HDIM);
  tcast_kernel<<<dim3(NE * 64), dim3(256), 0, stream>>>(wproj, wprojT, HDIM, DDIM);
  xcast_kernel<<<dim3(2048), dim3(256), 0, stream>>>(x, Xb, (long)NE * CAPN * DDIM / 8);

  const int ngroups = NE / ne;
  for (int g = 0; g < ngroups; ++g) {
    const int e0 = g * ne;
    gemm_8p<8, 4, 1024, 256, 256, true>
        <<<dim3(ne * 64), dim3(512), 131072, stream>>>(wfcT, Xb, Hb, e0);
    gemm_8p<32, 1, 4096, 1024, 1024, false>
        <<<dim3(ne * 16), dim3(512), 131072, stream>>>(Hb, wprojT, out, e0);
  }
}